// Round 1
// baseline (508.536 us; speedup 1.0000x reference)
//
#include <hip/hip_runtime.h>

#define NLVL 16
#define NTOT 1846083
#define NBLK 16140

typedef float  f32x4  __attribute__((ext_vector_type(4)));
typedef __bf16 bf16x8 __attribute__((ext_vector_type(8)));
typedef __bf16 bf16x4 __attribute__((ext_vector_type(4)));
typedef unsigned int u32x4 __attribute__((ext_vector_type(4)));

// compile-time level tables (resolutions/offsets are static in the reference)
__constant__ int c_R[NLVL]      = {16,18,20,22,25,27,30,34,38,42,47,52,58,64,72,80};
__constant__ int c_off[NLVL]    = {0,4096,9928,17928,28576,44201,63884,90884,130188,185060,259148,362971,503579,698691,960835,1334083};
__constant__ int c_czy[NLVL]    = {4,5,5,6,7,7,8,9,10,11,12,13,15,16,18,20};   // ceil(R/4)
__constant__ int c_cx[NLVL]     = {1,2,2,2,2,2,2,3,3,3,3,4,4,4,5,5};           // ceil(R/16)
__constant__ int c_base[NLVL+1] = {0,32,132,232,376,572,768,1024,1510,2110,2836,3700,5052,6852,8900,12140,16140};

// pre-packed B fragments: [level][pair(14)][lane(64)][8 bf16] = 229 KB
__device__ __align__(16) unsigned short g_bfrag[NLVL*14*64*8];

// ---------------------------------------------------------------------------
// Pre-kernel: pack weights into MFMA B-operand fragments (bf16).
// B[k][n]: lane holds n = lane&15, k = (lane>>4)*8 + j (j=0..7).
// k -> (tap_in_pair = k>>4, ci = k&15); tap = 2*pair + tap_in_pair.
// ---------------------------------------------------------------------------
__global__ void prep_bfrag(const float* __restrict__ wgt) {
    int tid = blockIdx.x * 256 + threadIdx.x;
    if (tid >= NLVL*14*64) return;
    int lane = tid & 63;
    int p    = (tid >> 6) % 14;
    int l    = tid / (14*64);
    int quad = lane >> 4, co = lane & 15;
    unsigned short v[8];
#pragma unroll
    for (int j = 0; j < 8; ++j) {
        int k  = quad*8 + j;
        int t  = 2*p + (k >> 4);
        int ci = k & 15;
        float f = (t < 27) ? wgt[((l*27 + t)*16 + ci)*16 + co] : 0.f;
        v[j] = __builtin_bit_cast(unsigned short, (__bf16)f);
    }
    u32x4 pk;
    pk[0] = (unsigned)v[0] | ((unsigned)v[1] << 16);
    pk[1] = (unsigned)v[2] | ((unsigned)v[3] << 16);
    pk[2] = (unsigned)v[4] | ((unsigned)v[5] << 16);
    pk[3] = (unsigned)v[6] | ((unsigned)v[7] << 16);
    *(u32x4*)&g_bfrag[(size_t)tid*8] = pk;
}

// ---------------------------------------------------------------------------
// Main kernel: implicit-GEMM 3D conv. Block = 4 waves; tile = 16x * 4y * 4z.
// ---------------------------------------------------------------------------
__global__ void conv_kernel(const float* __restrict__ in,
                            const float* __restrict__ bias,
                            float* __restrict__ out) {
    // slab[z' 0..5][y' 0..5][x' 0..17][ci 0..15], bf16, 20736 B
    __shared__ __align__(16) __bf16 slab[6*6*18*16];

    const int bid = blockIdx.x;
    int l = 0;
#pragma unroll
    for (int i = 1; i < NLVL; ++i) if (bid >= c_base[i]) l = i;
    const int R = c_R[l], off = c_off[l], czy = c_czy[l], cx = c_cx[l];

    int local = bid - c_base[l];
    int per_b = czy*czy*cx;
    int bb = local / per_b;       int r1 = local - bb*per_b;
    int zt = r1 / (czy*cx);       int r2 = r1 - zt*(czy*cx);
    int yt = r2 / cx;             int xt = r2 - yt*cx;
    const int z0 = zt*4, y0 = yt*4, x0 = xt*16;

    // ---- stage input slab fp32 -> bf16, zero OOB (SAME padding + edges) ----
    const int tid = threadIdx.x;
    for (int c = tid; c < 2592; c += 256) {          // 36 rows * 72 float4
        int row = c / 72;  int pos = c - row*72;
        int zp = row / 6;  int yp  = row - zp*6;
        int xp = pos >> 2; int ci4 = (pos & 3) << 2;
        int z = z0 + zp - 1, y = y0 + yp - 1, x = x0 + xp - 1;
        f32x4 v = {0.f, 0.f, 0.f, 0.f};
        if ((unsigned)z < (unsigned)R && (unsigned)y < (unsigned)R && (unsigned)x < (unsigned)R) {
            long e = ((long)bb*NTOT + off + ((z*R + y)*R + x)) * 16 + ci4;
            v = *(const f32x4*)(in + e);
        }
        bf16x4 h = { (__bf16)v[0], (__bf16)v[1], (__bf16)v[2], (__bf16)v[3] };
        *(bf16x4*)&slab[(row*18 + xp)*16 + ci4] = h;
    }

    // ---- per-lane B fragments (loaded while staging is in flight) ----
    const int lane = tid & 63;
    const int wv   = tid >> 6;           // wave id -> y row
    const int quad = lane >> 4;
    const int co   = lane & 15;          // C/D column (= A row index too)
    const int m    = lane & 15;          // A row (voxel in x)
    const int qh   = quad >> 1;          // which tap of the pair this quad reads
    bf16x8 bf[14];
#pragma unroll
    for (int p = 0; p < 14; ++p)
        bf[p] = *(const bf16x8*)&g_bfrag[(size_t)((l*14 + p)*64 + lane)*8];

    __syncthreads();

    // ---- K loop: 27 taps as 14 pairs (pair 13 second-half has B=0) ----
    f32x4 acc0 = {0,0,0,0}, acc1 = {0,0,0,0}, acc2 = {0,0,0,0}, acc3 = {0,0,0,0};
    const char* sb = (const char*)slab;
    const int abase = wv*576 + m*32 + (quad & 1)*16;   // bytes
#pragma unroll
    for (int p = 0; p < 14; ++p) {
        const int t0 = 2*p;
        const int t1 = (2*p + 1 > 26) ? 26 : 2*p + 1;
        const int c0 = (t0/9)*3456 + ((t0%9)/3)*576 + (t0%3)*32;
        const int c1 = (t1/9)*3456 + ((t1%9)/3)*576 + (t1%3)*32;
        const char* ap = sb + abase + (qh ? c1 : c0);
        bf16x8 a0 = *(const bf16x8*)(ap);
        bf16x8 a1 = *(const bf16x8*)(ap + 3456);
        bf16x8 a2 = *(const bf16x8*)(ap + 2*3456);
        bf16x8 a3 = *(const bf16x8*)(ap + 3*3456);
        acc0 = __builtin_amdgcn_mfma_f32_16x16x32_bf16(a0, bf[p], acc0, 0, 0, 0);
        acc1 = __builtin_amdgcn_mfma_f32_16x16x32_bf16(a1, bf[p], acc1, 0, 0, 0);
        acc2 = __builtin_amdgcn_mfma_f32_16x16x32_bf16(a2, bf[p], acc2, 0, 0, 0);
        acc3 = __builtin_amdgcn_mfma_f32_16x16x32_bf16(a3, bf[p], acc3, 0, 0, 0);
    }

    // ---- epilogue: D[row=quad*4+r][col=co], add bias, masked store ----
    const int yw = y0 + wv;
    if (yw >= R) return;
    const float bv = bias[(l << 4) + co];
    const long obase = (long)bb*NTOT + off;
    f32x4 accs[4] = {acc0, acc1, acc2, acc3};
#pragma unroll
    for (int zi = 0; zi < 4; ++zi) {
        int z = z0 + zi;
        if (z >= R) break;
        long rb = (obase + ((long)z*R + yw)*R) * 16 + co;
#pragma unroll
        for (int rr = 0; rr < 4; ++rr) {
            int x = x0 + quad*4 + rr;
            if (x < R) out[rb + (long)x*16] = accs[zi][rr] + bv;
        }
    }
}

extern "C" void kernel_launch(void* const* d_in, const int* in_sizes, int n_in,
                              void* d_out, int out_size, void* d_ws, size_t ws_size,
                              hipStream_t stream) {
    const float* inp = (const float*)d_in[0];
    const float* wgt = (const float*)d_in[1];
    const float* bia = (const float*)d_in[2];
    float* out = (float*)d_out;
    prep_bfrag<<<dim3(56), dim3(256), 0, stream>>>(wgt);
    conv_kernel<<<dim3(NBLK), dim3(256), 0, stream>>>(inp, bia, out);
}

// Round 2
// 440.345 us; speedup vs baseline: 1.1549x; 1.1549x over previous
//
#include <hip/hip_runtime.h>

#define NLVL 16
#define NTOT 1846083
#define NBLK 4376

typedef float  f32x4  __attribute__((ext_vector_type(4)));
typedef __bf16 bf16x8 __attribute__((ext_vector_type(8)));
typedef __bf16 bf16x4 __attribute__((ext_vector_type(4)));
typedef unsigned int u32x4 __attribute__((ext_vector_type(4)));

// level tables (static in reference)
__constant__ int c_R[NLVL]   = {16,18,20,22,25,27,30,34,38,42,47,52,58,64,72,80};
__constant__ int c_off[NLVL] = {0,4096,9928,17928,28576,44201,63884,90884,130188,185060,259148,362971,503579,698691,960835,1334083};
__constant__ int c_czy[NLVL] = {4,5,5,6,7,7,8,9,10,11,12,13,15,16,18,20};   // ceil(R/4)
__constant__ int c_cx[NLVL]  = {1,2,2,2,2,2,2,3,3,3,3,4,4,4,5,5};           // ceil(R/16) (= z-chunks too)
// blocks ordered level 15 -> 0 (longest first); count[l] = 2*czy*cx*cx
__constant__ int c_base[17]  = {0,1000,1900,2412,2892,3308,3524,3722,3902,4064,4128,4184,4240,4288,4328,4368,4376};

// B fragments: [level][kz(3)][pair(5)][lane(64)][8 bf16] = 240 KB
__device__ __align__(16) unsigned short g_bfrag[NLVL*3*5*64*8];

// ---------------------------------------------------------------------------
// Pack weights into MFMA B fragments. B[k][n]: n=lane&15, k=(lane>>4)*8+j.
// k -> tap_in_pair = k>>4, ci = k&15; in-plane tap t2 = 2*pair + tip (9 taps,
// t2==9 padded with zero).
// ---------------------------------------------------------------------------
__global__ void prep_bfrag(const float* __restrict__ wgt) {
    int tid = blockIdx.x * 256 + threadIdx.x;
    if (tid >= NLVL*3*5*64) return;
    int lane = tid & 63;
    int p    = (tid >> 6) % 5;
    int d    = (tid / (5*64)) % 3;
    int l    = tid / (3*5*64);
    int quad = lane >> 4, co = lane & 15;
    unsigned short v[8];
#pragma unroll
    for (int j = 0; j < 8; ++j) {
        int k   = quad*8 + j;
        int tip = k >> 4;
        int ci  = k & 15;
        int t2  = 2*p + tip;
        float f = (t2 < 9) ? wgt[((l*27 + d*9 + t2)*16 + ci)*16 + co] : 0.f;
        v[j] = __builtin_bit_cast(unsigned short, (__bf16)f);
    }
    u32x4 pk;
    pk[0] = (unsigned)v[0] | ((unsigned)v[1] << 16);
    pk[1] = (unsigned)v[2] | ((unsigned)v[3] << 16);
    pk[2] = (unsigned)v[4] | ((unsigned)v[5] << 16);
    pk[3] = (unsigned)v[6] | ((unsigned)v[7] << 16);
    *(u32x4*)&g_bfrag[(size_t)tid*8] = pk;
}

// ---------------------------------------------------------------------------
// Streaming-z conv: block = 4 waves, tile 16x * 4y, z-chunk of 16.
// Per z-step: stage plane z+1 (double-buffered LDS, one barrier/step),
// 5 A-frag ds_reads reused across 3 kz -> 15 MFMA into rolling accs.
// ---------------------------------------------------------------------------
__global__ __launch_bounds__(256, 3)
void conv_kernel(const float* __restrict__ in,
                 const float* __restrict__ bias,
                 float* __restrict__ out) {
    // two planes: [yp 0..5][xp 0..17][ci 0..15] bf16 = 3456 B each
    __shared__ __align__(16) __bf16 slab[2*1728];

    const int bid = blockIdx.x;
    int idx = 0;
#pragma unroll
    for (int i = 1; i < 16; ++i) if (bid >= c_base[i]) idx = i;
    const int l = 15 - idx;
    const int R = c_R[l], off = c_off[l], czy = c_czy[l], cx = c_cx[l];

    int local = bid - c_base[idx];
    int per_b = czy*cx*cx;
    int bb = local / per_b;         int r1 = local - bb*per_b;
    int zt = r1 / (czy*cx);         int r2 = r1 - zt*(czy*cx);
    int yt = r2 / cx;               int xt = r2 - yt*cx;
    const int z0 = zt*16;
    const int z1 = (z0 + 16 < R) ? z0 + 16 : R;
    const int y0 = yt*4, x0 = xt*16;

    // ---- per-lane constants ----
    const int t    = threadIdx.x;
    const int lane = t & 63;
    const int wv   = t >> 6;
    const int quad = lane >> 4;
    const int co   = lane & 15;
    const int m    = lane & 15;
    const int qh   = quad >> 1;

    // ---- B fragments resident (15 x 16B per lane) ----
    bf16x8 bfr[15];
#pragma unroll
    for (int d = 0; d < 3; ++d)
#pragma unroll
        for (int p = 0; p < 5; ++p)
            bfr[d*5+p] = *(const bf16x8*)&g_bfrag[(size_t)(((l*3 + d)*5 + p)*64 + lane)*8];

    // ---- A-frag byte offsets within a plane (5 pairs) ----
    // toff(t2) = (t2/3)*576 + (t2%3)*32 ; qh picks tap within pair
    const int albase = wv*576 + m*32 + (quad & 1)*16;
    int aoff[5];
    {
        const int T0[5] = {0, 64, 608, 1152, 1216};
        const int T1[5] = {32, 576, 640, 1184, 1216};
#pragma unroll
        for (int p = 0; p < 5; ++p) aoff[p] = albase + (qh ? T1[p] : T0[p]);
    }

    // ---- staging precompute: plane = 432 float4; thread does c and c+256 ----
    const long zs = (long)R*R*16;
    long g0 = 0, g1 = 0; int lo0 = 0, lo1 = 0; bool yx0 = false, yx1 = false;
    {
        int c = t;
        int yp = c/72; int rem = c - yp*72; int xp = rem>>2; int ci4 = (rem&3)<<2;
        lo0 = (yp*18 + xp)*16 + ci4;
        int y = y0 + yp - 1, x = x0 + xp - 1;
        yx0 = ((unsigned)y < (unsigned)R) && ((unsigned)x < (unsigned)R);
        g0 = ((long)bb*NTOT + off)*16 + ((long)y*R + x)*16 + ci4;
    }
    const bool has1 = (t < 176);
    if (has1) {
        int c = t + 256;
        int yp = c/72; int rem = c - yp*72; int xp = rem>>2; int ci4 = (rem&3)<<2;
        lo1 = (yp*18 + xp)*16 + ci4;
        int y = y0 + yp - 1, x = x0 + xp - 1;
        yx1 = ((unsigned)y < (unsigned)R) && ((unsigned)x < (unsigned)R);
        g1 = ((long)bb*NTOT + off)*16 + ((long)y*R + x)*16 + ci4;
    }

    __bf16* sbr = slab;          // plane being read
    __bf16* sbw = slab + 1728;   // plane being written

    // ---- prologue: stage plane z0-1 into sbr ----
    {
        int zn = z0 - 1;
        bool zok = (unsigned)zn < (unsigned)R;
        f32x4 v0 = {0,0,0,0}, v1 = {0,0,0,0};
        if (zok && yx0) v0 = *(const f32x4*)(in + g0 + (long)zn*zs);
        if (has1 && zok && yx1) v1 = *(const f32x4*)(in + g1 + (long)zn*zs);
        bf16x4 h0 = {(__bf16)v0[0],(__bf16)v0[1],(__bf16)v0[2],(__bf16)v0[3]};
        *(bf16x4*)(sbr + lo0) = h0;
        if (has1) {
            bf16x4 h1 = {(__bf16)v1[0],(__bf16)v1[1],(__bf16)v1[2],(__bf16)v1[3]};
            *(bf16x4*)(sbr + lo1) = h1;
        }
    }
    __syncthreads();

    const bool ywok = (y0 + wv) < R;
    const float bv = bias[(l << 4) + co];
    const long obase = ((long)bb*NTOT + off)*16;

    f32x4 accA = {0,0,0,0}, accB = {0,0,0,0}, accC = {0,0,0,0};
    const int steps = z1 - z0 + 2;

    for (int i = 0; i < steps; ++i) {
        const int zp = z0 - 1 + i;
        const int zn = zp + 1;
        const bool sok = (zn <= z1);

        // issue staging loads early (overlap with MFMA below)
        f32x4 v0 = {0,0,0,0}, v1 = {0,0,0,0};
        if (sok) {
            bool zok = (unsigned)zn < (unsigned)R;
            if (zok && yx0) v0 = *(const f32x4*)(in + g0 + (long)zn*zs);
            if (has1 && zok && yx1) v1 = *(const f32x4*)(in + g1 + (long)zn*zs);
        }

        // compute: 5 A frags from current plane, reused for 3 kz groups
        const char* sb = (const char*)sbr;
#pragma unroll
        for (int p = 0; p < 5; ++p) {
            bf16x8 a = *(const bf16x8*)(sb + aoff[p]);
            accC = __builtin_amdgcn_mfma_f32_16x16x32_bf16(a, bfr[p],      accC, 0, 0, 0); // kz=0 -> out zp+1
            accB = __builtin_amdgcn_mfma_f32_16x16x32_bf16(a, bfr[5+p],  accB, 0, 0, 0);   // kz=1 -> out zp
            accA = __builtin_amdgcn_mfma_f32_16x16x32_bf16(a, bfr[10+p], accA, 0, 0, 0);   // kz=2 -> out zp-1
        }

        // write staged plane zn into the other buffer
        if (sok) {
            bf16x4 h0 = {(__bf16)v0[0],(__bf16)v0[1],(__bf16)v0[2],(__bf16)v0[3]};
            *(bf16x4*)(sbw + lo0) = h0;
            if (has1) {
                bf16x4 h1 = {(__bf16)v1[0],(__bf16)v1[1],(__bf16)v1[2],(__bf16)v1[3]};
                *(bf16x4*)(sbw + lo1) = h1;
            }
        }

        // output zp-1 completed (accA)
        if (i >= 2 && ywok) {
            int z = zp - 1;
            long rb = obase + (((long)z*R + (y0 + wv))*R)*16 + co;
#pragma unroll
            for (int rr = 0; rr < 4; ++rr) {
                int x = x0 + quad*4 + rr;
                if (x < R) out[rb + (long)x*16] = accA[rr] + bv;
            }
        }

        // rotate accumulators
        accA = accB; accB = accC;
        accC = (f32x4){0,0,0,0};

        __syncthreads();
        __bf16* tmp = sbr; sbr = sbw; sbw = tmp;
    }
}

extern "C" void kernel_launch(void* const* d_in, const int* in_sizes, int n_in,
                              void* d_out, int out_size, void* d_ws, size_t ws_size,
                              hipStream_t stream) {
    const float* inp = (const float*)d_in[0];
    const float* wgt = (const float*)d_in[1];
    const float* bia = (const float*)d_in[2];
    float* out = (float*)d_out;
    prep_bfrag<<<dim3((NLVL*3*5*64 + 255)/256), dim3(256), 0, stream>>>(wgt);
    conv_kernel<<<dim3(NBLK), dim3(256), 0, stream>>>(inp, bia, out);
}